// Round 13
// baseline (61.994 us; speedup 1.0000x reference)
//
#include <hip/hip_runtime.h>
#include <hip/hip_bf16.h>
#include <stdint.h>

#if __has_builtin(__builtin_amdgcn_cvt_pk_f32_fp8) && __has_builtin(__builtin_amdgcn_cvt_pk_fp8_f32)
#define HAS_HW_FP8 1
#else
#define HAS_HW_FP8 0
#include <hip/hip_fp8.h>
#endif

#if __has_builtin(__builtin_amdgcn_cvt_pk_f16_fp8)
#define HAS_F16_FP8 1
#else
#define HAS_F16_FP8 0
#endif

// Problem constants (from reference)
#define B_  2
#define F_  2
#define C_  64
#define D_  96
#define HM_ 48
#define WM_ 160
#define HW_ (HM_ * WM_)                 // 7680
#define NTOT ((size_t)B_ * D_ * HW_)    // 1,474,560 per output tensor
#define EPS_ 1e-7f
#define DW_  4                          // depths per block (one per wave)
#define NDG_ (D_ / DW_)                 // 24 depth groups

typedef _Float16 half_t;
typedef _Float16 h2 __attribute__((ext_vector_type(2)));
typedef float f2 __attribute__((ext_vector_type(2)));
typedef unsigned int u32;

// 16B: NEGATED cur, 8 f16 channels as 4 pairs
struct CH8 { h2 c01, c23, c45, c67; };

// fp8 quad entry (16B): .x=p00, .y=p01, .z=p10, .w=p11; each u32 = 4 channels
// (c0..c3) as e4m3 bytes.

__device__ __forceinline__ u32 pk4_fp8(float a, float b, float c, float d) {
#if HAS_HW_FP8
    int r = __builtin_amdgcn_cvt_pk_fp8_f32(a, b, 0, false);
    r = __builtin_amdgcn_cvt_pk_fp8_f32(c, d, r, true);
    return (u32)r;
#else
    __hip_fp8_e4m3 qa(a), qb(b), qc(c), qd(d);
    return (u32)qa.__x | ((u32)qb.__x << 8) | ((u32)qc.__x << 16) |
           ((u32)qd.__x << 24);
#endif
}

template <bool HI>
__device__ __forceinline__ f2 fp8pk_f32(u32 v) {
#if HAS_HW_FP8
    return __builtin_amdgcn_cvt_pk_f32_fp8((int)v, HI);
#else
    u32 w = HI ? (v >> 16) : v;
    __hip_fp8_e4m3 q0, q1;
    q0.__x = (uint8_t)(w & 0xff);
    q1.__x = (uint8_t)((w >> 8) & 0xff);
    f2 r; r.x = (float)q0; r.y = (float)q1;
    return r;
#endif
}

// fp8 pair -> f16 pair (1 instr on gfx950; fallback via f32)
template <bool HI>
__device__ __forceinline__ h2 fp8pk_f16(u32 v) {
#if HAS_F16_FP8
    return __builtin_amdgcn_cvt_pk_f16_fp8((int)v, HI);
#else
    f2 f = fp8pk_f32<HI>(v);
    return h2{(half_t)f.x, (half_t)f.y};
#endif
}

__device__ __forceinline__ h2 pabs(h2 v) {
    u32 u; __builtin_memcpy(&u, &v, 4);
    u &= 0x7FFF7FFFu;
    h2 r; __builtin_memcpy(&r, &u, 4);
    return r;
}

#if __has_builtin(__builtin_amdgcn_fdot2)
__device__ __forceinline__ float FDOT2(h2 a, h2 b, float c) {
    return __builtin_amdgcn_fdot2(a, b, c, false);
}
#else
__device__ __forceinline__ float FDOT2(h2 a, h2 b, float c) {
    return (float)a.x * (float)b.x + (float)a.y * (float)b.y + c;
}
#endif

#define NQBLK4 ((B_ * F_ * (C_/4) * (HW_/4)) / 256)  // 480
#define NCBLK8 ((B_ * (C_/8) * HW_) / 256)           // 480

// ---------------------------------------------------------------------------
// Pack:
//  * quad4 [n][C/4][HW] (16B): corner-major fp8 quads, 4 channels per entry.
//    4 pixels per thread via aligned float4 row loads.
//  * cur8  [b][C/8][HW] (16B): 8 NEGATED f16 cur channels
// Block 0 also computes P = (K@T)[:3] and pose validity.
// ---------------------------------------------------------------------------
__global__ __launch_bounds__(256) void pack_and_setup(
    const float* __restrict__ look,   // [B*F*C][HW]
    const float* __restrict__ cur,    // [B*C][HW]
    uint4* __restrict__ quad4,
    CH8* __restrict__ cur8,
    const float* __restrict__ poses,
    const float* __restrict__ K,
    float* __restrict__ Pout,         // [B*F][12]
    float* __restrict__ validOut)     // [B*F]
{
    if (blockIdx.x == 0 && threadIdx.x < 64) {
        int t = threadIdx.x;
        if (t < B_ * F_ * 12) {
            int j  = t & 3;
            int i  = (t >> 2) % 3;
            int bf = t / 12;
            int b  = bf / F_;
            const float* Kb = K + (size_t)b * 16;
            const float* T  = poses + (size_t)bf * 16;
            float s = 0.f;
            #pragma unroll
            for (int k = 0; k < 4; ++k) s += Kb[i * 4 + k] * T[k * 4 + j];
            Pout[bf * 12 + i * 4 + j] = s;
        }
        if (t < B_ * F_) {
            const float* T = poses + (size_t)t * 16;
            float s = 0.f;
            #pragma unroll
            for (int k = 0; k < 16; ++k) s += T[k];
            validOut[t] = (s != 0.0f) ? 1.0f : 0.0f;
        }
    }

    int blk = blockIdx.x;
    if (blk < NQBLK4) {
        int t   = blk * 256 + threadIdx.x;     // B*F*(C/4)*(HW/4)
        int g   = t % (HW_ / 4);               // 4-pixel group (same row)
        int rem = t / (HW_ / 4);
        int c4  = rem % (C_ / 4);
        int n   = rem / (C_ / 4);
        int x0 = (g * 4) % WM_;
        int y  = (g * 4) / WM_;
        int y1 = min(y + 1, HM_ - 1);
        int xe = min(x0 + 4, WM_ - 1);

        const float* base = look + ((size_t)n * C_ + 4 * c4) * HW_;
        float4 rA[4], rB[4];
        float  eA[4], eB[4];
        #pragma unroll
        for (int k = 0; k < 4; ++k) {
            const float* bc = base + (size_t)k * HW_;
            rA[k] = *(const float4*)(bc + y  * WM_ + x0);
            eA[k] = bc[y  * WM_ + xe];
            rB[k] = *(const float4*)(bc + y1 * WM_ + x0);
            eB[k] = bc[y1 * WM_ + xe];
        }
        const float* fA[4] = {(const float*)&rA[0], (const float*)&rA[1],
                              (const float*)&rA[2], (const float*)&rA[3]};
        const float* fB[4] = {(const float*)&rB[0], (const float*)&rB[1],
                              (const float*)&rB[2], (const float*)&rB[3]};

        uint4* outp = quad4 + ((size_t)(n * (C_ / 4) + c4)) * HW_ + g * 4;
        #pragma unroll
        for (int j = 0; j < 4; ++j) {
            float p01_0 = (j < 3) ? fA[0][j + 1] : eA[0];
            float p01_1 = (j < 3) ? fA[1][j + 1] : eA[1];
            float p01_2 = (j < 3) ? fA[2][j + 1] : eA[2];
            float p01_3 = (j < 3) ? fA[3][j + 1] : eA[3];
            float p11_0 = (j < 3) ? fB[0][j + 1] : eB[0];
            float p11_1 = (j < 3) ? fB[1][j + 1] : eB[1];
            float p11_2 = (j < 3) ? fB[2][j + 1] : eB[2];
            float p11_3 = (j < 3) ? fB[3][j + 1] : eB[3];
            uint4 q;
            q.x = pk4_fp8(fA[0][j], fA[1][j], fA[2][j], fA[3][j]);
            q.y = pk4_fp8(p01_0,    p01_1,    p01_2,    p01_3);
            q.z = pk4_fp8(fB[0][j], fB[1][j], fB[2][j], fB[3][j]);
            q.w = pk4_fp8(p11_0,    p11_1,    p11_2,    p11_3);
            outp[j] = q;
        }
    } else {
        int t   = (blk - NQBLK4) * 256 + threadIdx.x;  // B*(C/8)*HW
        int pix = t % HW_;
        int rem = t / HW_;
        int c8  = rem % (C_ / 8);
        int b   = rem / (C_ / 8);
        const float* p = cur + ((size_t)b * C_ + 8 * c8) * HW_ + pix;
        CH8 h;
        h.c01 = h2{(half_t)(-p[0]),               (half_t)(-p[(size_t)HW_])};
        h.c23 = h2{(half_t)(-p[2 * (size_t)HW_]), (half_t)(-p[3 * (size_t)HW_])};
        h.c45 = h2{(half_t)(-p[4 * (size_t)HW_]), (half_t)(-p[5 * (size_t)HW_])};
        h.c67 = h2{(half_t)(-p[6 * (size_t)HW_]), (half_t)(-p[7 * (size_t)HW_])};
        cur8[t] = h;
    }
}

// ---------------------------------------------------------------------------
// Main cost-volume kernel. One thread per output (b,d,hw); block's 4 waves =
// 4 consecutive depths of the same 64-pixel segment. Per 8-channel group:
// 5 loads (4x16B fp8 quad + 1x16B f16 negcur), v_cvt_pk_f16_fp8 unpack
// (1 instr / 2 values), v_pk_fma_f16 bilinear chained from negated cur,
// packed abs+add, FDOT2 drain to f32 every 8 channels.
// ---------------------------------------------------------------------------
__global__ __launch_bounds__(256) void cost_volume(
    const uint4* __restrict__ quad4,   // [B*F][C/4][HW]
    const CH8* __restrict__ cur8,      // [B][C/8][HW]
    const float* __restrict__ invK,    // [B][16]
    const float* __restrict__ P,       // [B*F][12]
    const float* __restrict__ validF,  // [B*F]
    float* __restrict__ cvOut)         // [B][D][HW]
{
    int blk  = blockIdx.x;             // 5760 = 120 tile64 * (B_*NDG_)
    int tile = blk / (B_ * NDG_);
    int r    = blk % (B_ * NDG_);
    int b    = r / NDG_;
    int dg   = r % NDG_;
    int wave = threadIdx.x >> 6;
    int lane = threadIdx.x & 63;
    int d    = dg * DW_ + wave;
    int hw   = tile * 64 + lane;

    int x = hw % WM_, y = hw / WM_;
    float fx = (float)x, fy = (float)y;

    const float* ik = invK + (size_t)b * 16;
    float rx = ik[0] * fx + ik[1] * fy + ik[2];
    float ry = ik[4] * fx + ik[5] * fy + ik[6];
    float rz = ik[8] * fx + ik[9] * fy + ik[10];

    float depth = 0.1f + (float)d * (19.9f / 95.0f);
    float qx = depth * rx, qy = depth * ry, qz = depth * rz;

    bool inter = (x >= 2 && x <= WM_ - 3 && y >= 2 && y <= HM_ - 3);

    unsigned pixc[F_];
    float wf[F_][4];
    float ff[F_];

    #pragma unroll
    for (int f = 0; f < F_; ++f) {
        const float* Pf = P + (size_t)(b * F_ + f) * 12;
        float cp0 = Pf[0] * qx + Pf[1] * qy + Pf[2]  * qz + Pf[3];
        float cp1 = Pf[4] * qx + Pf[5] * qy + Pf[6]  * qz + Pf[7];
        float cp2 = Pf[8] * qx + Pf[9] * qy + Pf[10] * qz + Pf[11];
        float z  = cp2 + EPS_;
        float gx = cp0 / z, gy = cp1 / z;

        float x0f = floorf(gx), y0f = floorf(gy);
        float wx1 = gx - x0f, wy1 = gy - y0f;
        float wx0 = 1.f - wx1, wy0 = 1.f - wy1;

        int x0 = (int)x0f, y0 = (int)y0f;
        int cx = min(max(x0, 0), WM_ - 1);
        int cy = min(max(y0, 0), HM_ - 1);
        pixc[f] = (unsigned)(cy * WM_ + cx);

        wf[f][0] = wx0 * wy0;
        wf[f][1] = wx1 * wy0;
        wf[f][2] = wx0 * wy1;
        wf[f][3] = wx1 * wy1;

        bool e = (gx >= 2.f) && (gx <= (float)(WM_ - 2)) &&
                 (gy >= 2.f) && (gy <= (float)(HM_ - 2)) && inter;
        ff[f] = (e ? 1.f : 0.f) * validF[b * F_ + f];
    }

    size_t oidx = ((size_t)(b * D_ + d)) * HW_ + hw;

    // Wave-uniform early-out
    if (__ballot(ff[0] > 0.f || ff[1] > 0.f) == 0ull) {
        cvOut[oidx] = 0.f;
        return;
    }

    // duplicated f16 weight pairs per frame
    h2 W00_0 = h2{(half_t)wf[0][0], (half_t)wf[0][0]};
    h2 W01_0 = h2{(half_t)wf[0][1], (half_t)wf[0][1]};
    h2 W10_0 = h2{(half_t)wf[0][2], (half_t)wf[0][2]};
    h2 W11_0 = h2{(half_t)wf[0][3], (half_t)wf[0][3]};
    h2 W00_1 = h2{(half_t)wf[1][0], (half_t)wf[1][0]};
    h2 W01_1 = h2{(half_t)wf[1][1], (half_t)wf[1][1]};
    h2 W10_1 = h2{(half_t)wf[1][2], (half_t)wf[1][2]};
    h2 W11_1 = h2{(half_t)wf[1][3], (half_t)wf[1][3]};

    const char* qbp = (const char*)quad4;
    const char* cbp = (const char*)cur8;
    unsigned oA = ((u32)((b * F_ + 0) * (C_ / 4)) * HW_ + pixc[0]) * 16u;
    unsigned oB = ((u32)((b * F_ + 1) * (C_ / 4)) * HW_ + pixc[1]) * 16u;
    unsigned oc = ((u32)(b * (C_ / 8)) * HW_ + (u32)hw) * 16u;

    const h2 ones = h2{(half_t)1.f, (half_t)1.f};
    float s0 = 0.f, s1 = 0.f;

    #pragma unroll 2
    for (int g = 0; g < 8; ++g) {          // 8 groups x 8 channels
        uint4 qa0 = *(const uint4*)(qbp + oA);
        uint4 qa1 = *(const uint4*)(qbp + oA + (u32)HW_ * 16u);
        oA += (u32)HW_ * 32u;
        uint4 qb0 = *(const uint4*)(qbp + oB);
        uint4 qb1 = *(const uint4*)(qbp + oB + (u32)HW_ * 16u);
        oB += (u32)HW_ * 32u;
        CH8 cu = *(const CH8*)(cbp + oc); oc += (u32)HW_ * 16u;

        h2 t, hA, hB;

        // frame A
        t = fp8pk_f16<false>(qa0.w) * W11_0 + cu.c01;
        t = fp8pk_f16<false>(qa0.z) * W10_0 + t;
        t = fp8pk_f16<false>(qa0.y) * W01_0 + t;
        t = fp8pk_f16<false>(qa0.x) * W00_0 + t;
        hA = pabs(t);
        t = fp8pk_f16<true>(qa0.w) * W11_0 + cu.c23;
        t = fp8pk_f16<true>(qa0.z) * W10_0 + t;
        t = fp8pk_f16<true>(qa0.y) * W01_0 + t;
        t = fp8pk_f16<true>(qa0.x) * W00_0 + t;
        hA += pabs(t);
        t = fp8pk_f16<false>(qa1.w) * W11_0 + cu.c45;
        t = fp8pk_f16<false>(qa1.z) * W10_0 + t;
        t = fp8pk_f16<false>(qa1.y) * W01_0 + t;
        t = fp8pk_f16<false>(qa1.x) * W00_0 + t;
        hA += pabs(t);
        t = fp8pk_f16<true>(qa1.w) * W11_0 + cu.c67;
        t = fp8pk_f16<true>(qa1.z) * W10_0 + t;
        t = fp8pk_f16<true>(qa1.y) * W01_0 + t;
        t = fp8pk_f16<true>(qa1.x) * W00_0 + t;
        hA += pabs(t);
        s0 = FDOT2(hA, ones, s0);

        // frame B
        t = fp8pk_f16<false>(qb0.w) * W11_1 + cu.c01;
        t = fp8pk_f16<false>(qb0.z) * W10_1 + t;
        t = fp8pk_f16<false>(qb0.y) * W01_1 + t;
        t = fp8pk_f16<false>(qb0.x) * W00_1 + t;
        hB = pabs(t);
        t = fp8pk_f16<true>(qb0.w) * W11_1 + cu.c23;
        t = fp8pk_f16<true>(qb0.z) * W10_1 + t;
        t = fp8pk_f16<true>(qb0.y) * W01_1 + t;
        t = fp8pk_f16<true>(qb0.x) * W00_1 + t;
        hB += pabs(t);
        t = fp8pk_f16<false>(qb1.w) * W11_1 + cu.c45;
        t = fp8pk_f16<false>(qb1.z) * W10_1 + t;
        t = fp8pk_f16<false>(qb1.y) * W01_1 + t;
        t = fp8pk_f16<false>(qb1.x) * W00_1 + t;
        hB += pabs(t);
        t = fp8pk_f16<true>(qb1.w) * W11_1 + cu.c67;
        t = fp8pk_f16<true>(qb1.z) * W10_1 + t;
        t = fp8pk_f16<true>(qb1.y) * W01_1 + t;
        t = fp8pk_f16<true>(qb1.x) * W00_1 + t;
        hB += pabs(t);
        s1 = FDOT2(hB, ones, s1);
    }

    float m0 = s0 * (1.0f / 64.0f) * ff[0];
    float m1 = s1 * (1.0f / 64.0f) * ff[1];
    float costsum = m0 + m1;
    float counts  = ((m0 > 0.f) ? 1.f : 0.f) + ((m1 > 0.f) ? 1.f : 0.f);
    float scale = (counts > 1.5f) ? (1.0f / (2.0f + EPS_)) : (1.0f / (1.0f + EPS_));
    cvOut[oidx] = costsum * scale;
}

// ---------------------------------------------------------------------------
// Finalize: block = 64 pixels x 4 D-slices (one slice per wave). Each thread
// register-caches its 24 depths, LDS 4-way max combine, coalesced writes.
// ---------------------------------------------------------------------------
#define FDS_ 4
#define FDP_ (D_ / FDS_)   // 24

__global__ __launch_bounds__(256) void finalize(
    const float* __restrict__ cv,   // [B][D][HW]
    float* __restrict__ cost,       // [B][D][HW]
    float* __restrict__ missing)    // [B][D][HW]
{
    int slice = threadIdx.x >> 6;         // 0..3 (wave id)
    int lp    = threadIdx.x & 63;
    int p     = blockIdx.x * 64 + lp;     // 0..B*HW-1 (grid exact)
    int b = p / HW_, hw = p % HW_;
    const float* src = cv + (size_t)b * D_ * HW_ + (size_t)slice * FDP_ * HW_ + hw;

    float v[FDP_];
    float mx = 0.f;   // all values >= 0
    #pragma unroll
    for (int i = 0; i < FDP_; ++i) {
        v[i] = src[(size_t)i * HW_];
        mx = fmaxf(mx, v[i]);
    }

    __shared__ float lmax[FDS_][64];
    lmax[slice][lp] = mx;
    __syncthreads();
    mx = fmaxf(fmaxf(lmax[0][lp], lmax[1][lp]),
               fmaxf(lmax[2][lp], lmax[3][lp]));

    size_t obase = (size_t)b * D_ * HW_ + (size_t)slice * FDP_ * HW_ + hw;
    #pragma unroll
    for (int i = 0; i < FDP_; ++i) {
        float val = v[i];
        float m = (val == 0.f) ? 1.f : 0.f;
        size_t o = obase + (size_t)i * HW_;
        cost[o]    = (m != 0.f) ? mx : val;
        missing[o] = m;
    }
}

// ---------------------------------------------------------------------------
extern "C" void kernel_launch(void* const* d_in, const int* in_sizes, int n_in,
                              void* d_out, int out_size, void* d_ws, size_t ws_size,
                              hipStream_t stream)
{
    const float* current = (const float*)d_in[0];  // [B,C,H,W]
    const float* lookup  = (const float*)d_in[1];  // [B,F,C,H,W]
    const float* poses   = (const float*)d_in[2];  // [B,F,4,4]
    const float* K       = (const float*)d_in[3];  // [B,4,4]
    const float* invK    = (const float*)d_in[4];  // [B,4,4]

    float* out = (float*)d_out;
    float* costOut    = out;                 // [B,D,H,W]
    float* missingOut = out + NTOT;          // [B,D,H,W]
    float* cvOut      = out + 2 * NTOT;      // [B,D,H,W] (pre-fill cost)

    // workspace: params + 7.9 MB fp8 quad buffer
    float* ws     = (float*)d_ws;
    float* Pmat   = ws;                      // B*F*12 = 48 floats
    float* validF = Pmat + B_ * F_ * 12;     // B*F    = 4 floats
    uint4* quad4  = (uint4*)(ws + 64);       // B*F*(C/4)*HW * 16B = 7,864,320 B

    // cur8 stash lives in the costOut region (1.97 MB << 5.9 MB); it is
    // consumed by cost_volume and then overwritten by finalize.
    CH8* cur8 = (CH8*)costOut;

    const int npack = NQBLK4 + NCBLK8;           // 480 + 480 = 960
    hipLaunchKernelGGL(pack_and_setup, dim3(npack), dim3(256), 0, stream,
                       lookup, current, quad4, cur8, poses, K, Pmat, validF);

    const int nblocks = (HW_ / 64) * B_ * NDG_;  // 120 * 48 = 5760
    hipLaunchKernelGGL(cost_volume, dim3(nblocks), dim3(256), 0, stream,
                       quad4, cur8, invK, Pmat, validF, cvOut);

    const int nfin = (B_ * HW_) / 64;            // 240 blocks (256 thr: 64px x 4 slices)
    hipLaunchKernelGGL(finalize, dim3(nfin), dim3(256), 0, stream,
                       cvOut, costOut, missingOut);
}

// Round 14
// 59.088 us; speedup vs baseline: 1.0492x; 1.0492x over previous
//
#include <hip/hip_runtime.h>
#include <hip/hip_bf16.h>
#include <stdint.h>

#if __has_builtin(__builtin_amdgcn_cvt_pk_f32_fp8) && __has_builtin(__builtin_amdgcn_cvt_pk_fp8_f32)
#define HAS_HW_FP8 1
#else
#define HAS_HW_FP8 0
#include <hip/hip_fp8.h>
#endif

// Problem constants (from reference)
#define B_  2
#define F_  2
#define C_  64
#define D_  96
#define HM_ 48
#define WM_ 160
#define HW_ (HM_ * WM_)                 // 7680
#define NTOT ((size_t)B_ * D_ * HW_)    // 1,474,560 per output tensor
#define EPS_ 1e-7f
#define DW_  4                          // depths per block (one per wave)
#define NDG_ (D_ / DW_)                 // 24 depth groups

typedef float f2 __attribute__((ext_vector_type(2)));
typedef unsigned int u32;

// fp8 quad entry (16B): .x=p00, .y=p01, .z=p10, .w=p11; each u32 = 4 channels
// (c0..c3) as e4m3 bytes.

__device__ __forceinline__ u32 pk4_fp8(float a, float b, float c, float d) {
#if HAS_HW_FP8
    int r = __builtin_amdgcn_cvt_pk_fp8_f32(a, b, 0, false);
    r = __builtin_amdgcn_cvt_pk_fp8_f32(c, d, r, true);
    return (u32)r;
#else
    __hip_fp8_e4m3 qa(a), qb(b), qc(c), qd(d);
    return (u32)qa.__x | ((u32)qb.__x << 8) | ((u32)qc.__x << 16) |
           ((u32)qd.__x << 24);
#endif
}

template <bool HI>
__device__ __forceinline__ f2 fp8pk(u32 v) {
#if HAS_HW_FP8
    return __builtin_amdgcn_cvt_pk_f32_fp8((int)v, HI);
#else
    u32 w = HI ? (v >> 16) : v;
    __hip_fp8_e4m3 q0, q1;
    q0.__x = (uint8_t)(w & 0xff);
    q1.__x = (uint8_t)((w >> 8) & 0xff);
    f2 r; r.x = (float)q0; r.y = (float)q1;
    return r;
#endif
}

#define NQBLK4 ((B_ * F_ * (C_/4) * (HW_/4)) / 256)  // 480
#define NCBLK  ((B_ * (C_/4) * HW_) / 256)           // 960

// ---------------------------------------------------------------------------
// Pack:
//  * quad4 [n][C/4][HW] (16B): corner-major fp8 quads, 4 channels per entry.
//    4 pixels per thread via aligned float4 row loads.
//  * cur4  [b][C/4][HW] (16B float4): 4 NEGATED f32 cur channels (no cvt in cv)
// Block 0 also computes P = (K@T)[:3] and pose validity.
// ---------------------------------------------------------------------------
__global__ __launch_bounds__(256) void pack_and_setup(
    const float* __restrict__ look,   // [B*F*C][HW]
    const float* __restrict__ cur,    // [B*C][HW]
    uint4* __restrict__ quad4,
    float4* __restrict__ cur4,
    const float* __restrict__ poses,
    const float* __restrict__ K,
    float* __restrict__ Pout,         // [B*F][12]
    float* __restrict__ validOut)     // [B*F]
{
    if (blockIdx.x == 0 && threadIdx.x < 64) {
        int t = threadIdx.x;
        if (t < B_ * F_ * 12) {
            int j  = t & 3;
            int i  = (t >> 2) % 3;
            int bf = t / 12;
            int b  = bf / F_;
            const float* Kb = K + (size_t)b * 16;
            const float* T  = poses + (size_t)bf * 16;
            float s = 0.f;
            #pragma unroll
            for (int k = 0; k < 4; ++k) s += Kb[i * 4 + k] * T[k * 4 + j];
            Pout[bf * 12 + i * 4 + j] = s;
        }
        if (t < B_ * F_) {
            const float* T = poses + (size_t)t * 16;
            float s = 0.f;
            #pragma unroll
            for (int k = 0; k < 16; ++k) s += T[k];
            validOut[t] = (s != 0.0f) ? 1.0f : 0.0f;
        }
    }

    int blk = blockIdx.x;
    if (blk < NQBLK4) {
        int t   = blk * 256 + threadIdx.x;     // B*F*(C/4)*(HW/4)
        int g   = t % (HW_ / 4);               // 4-pixel group (same row)
        int rem = t / (HW_ / 4);
        int c4  = rem % (C_ / 4);
        int n   = rem / (C_ / 4);
        int x0 = (g * 4) % WM_;
        int y  = (g * 4) / WM_;
        int y1 = min(y + 1, HM_ - 1);
        int xe = min(x0 + 4, WM_ - 1);

        const float* base = look + ((size_t)n * C_ + 4 * c4) * HW_;
        float4 rA[4], rB[4];
        float  eA[4], eB[4];
        #pragma unroll
        for (int k = 0; k < 4; ++k) {
            const float* bc = base + (size_t)k * HW_;
            rA[k] = *(const float4*)(bc + y  * WM_ + x0);
            eA[k] = bc[y  * WM_ + xe];
            rB[k] = *(const float4*)(bc + y1 * WM_ + x0);
            eB[k] = bc[y1 * WM_ + xe];
        }
        const float* fA[4] = {(const float*)&rA[0], (const float*)&rA[1],
                              (const float*)&rA[2], (const float*)&rA[3]};
        const float* fB[4] = {(const float*)&rB[0], (const float*)&rB[1],
                              (const float*)&rB[2], (const float*)&rB[3]};

        uint4* outp = quad4 + ((size_t)(n * (C_ / 4) + c4)) * HW_ + g * 4;
        #pragma unroll
        for (int j = 0; j < 4; ++j) {
            float p01_0 = (j < 3) ? fA[0][j + 1] : eA[0];
            float p01_1 = (j < 3) ? fA[1][j + 1] : eA[1];
            float p01_2 = (j < 3) ? fA[2][j + 1] : eA[2];
            float p01_3 = (j < 3) ? fA[3][j + 1] : eA[3];
            float p11_0 = (j < 3) ? fB[0][j + 1] : eB[0];
            float p11_1 = (j < 3) ? fB[1][j + 1] : eB[1];
            float p11_2 = (j < 3) ? fB[2][j + 1] : eB[2];
            float p11_3 = (j < 3) ? fB[3][j + 1] : eB[3];
            uint4 q;
            q.x = pk4_fp8(fA[0][j], fA[1][j], fA[2][j], fA[3][j]);
            q.y = pk4_fp8(p01_0,    p01_1,    p01_2,    p01_3);
            q.z = pk4_fp8(fB[0][j], fB[1][j], fB[2][j], fB[3][j]);
            q.w = pk4_fp8(p11_0,    p11_1,    p11_2,    p11_3);
            outp[j] = q;
        }
    } else {
        int t   = (blk - NQBLK4) * 256 + threadIdx.x;  // B*(C/4)*HW
        int pix = t % HW_;
        int rem = t / HW_;
        int c4  = rem % (C_ / 4);
        int b   = rem / (C_ / 4);
        const float* p = cur + ((size_t)b * C_ + 4 * c4) * HW_ + pix;
        float4 h;
        h.x = -p[0];
        h.y = -p[(size_t)HW_];
        h.z = -p[2 * (size_t)HW_];
        h.w = -p[3 * (size_t)HW_];
        cur4[t] = h;
    }
}

// ---------------------------------------------------------------------------
// Main cost-volume kernel (r12 structure -- proven 48.5 us -- with cur in
// negated f32: same load count, 4 fewer cvts per iteration).
// One thread per output (b,d,hw); block's 4 waves = 4 consecutive depths of
// the same 64-pixel segment. Per 4 channels: 3 loads (2x16B fp8 quad +
// 1x16B f32 negcur), 16 v_cvt_pk_f32_fp8, f2 fma chain, f32 abs-accumulate.
// ---------------------------------------------------------------------------
__global__ __launch_bounds__(256) void cost_volume(
    const uint4* __restrict__ quad4,   // [B*F][C/4][HW]
    const float4* __restrict__ cur4,   // [B][C/4][HW] negated f32
    const float* __restrict__ invK,    // [B][16]
    const float* __restrict__ P,       // [B*F][12]
    const float* __restrict__ validF,  // [B*F]
    float* __restrict__ cvOut)         // [B][D][HW]
{
    int blk  = blockIdx.x;             // 5760 = 120 tile64 * (B_*NDG_)
    int tile = blk / (B_ * NDG_);
    int r    = blk % (B_ * NDG_);
    int b    = r / NDG_;
    int dg   = r % NDG_;
    int wave = threadIdx.x >> 6;
    int lane = threadIdx.x & 63;
    int d    = dg * DW_ + wave;
    int hw   = tile * 64 + lane;

    int x = hw % WM_, y = hw / WM_;
    float fx = (float)x, fy = (float)y;

    const float* ik = invK + (size_t)b * 16;
    float rx = ik[0] * fx + ik[1] * fy + ik[2];
    float ry = ik[4] * fx + ik[5] * fy + ik[6];
    float rz = ik[8] * fx + ik[9] * fy + ik[10];

    float depth = 0.1f + (float)d * (19.9f / 95.0f);
    float qx = depth * rx, qy = depth * ry, qz = depth * rz;

    bool inter = (x >= 2 && x <= WM_ - 3 && y >= 2 && y <= HM_ - 3);

    unsigned pixc[F_];
    float wf[F_][4];
    float ff[F_];

    #pragma unroll
    for (int f = 0; f < F_; ++f) {
        const float* Pf = P + (size_t)(b * F_ + f) * 12;
        float cp0 = Pf[0] * qx + Pf[1] * qy + Pf[2]  * qz + Pf[3];
        float cp1 = Pf[4] * qx + Pf[5] * qy + Pf[6]  * qz + Pf[7];
        float cp2 = Pf[8] * qx + Pf[9] * qy + Pf[10] * qz + Pf[11];
        float z  = cp2 + EPS_;
        float gx = cp0 / z, gy = cp1 / z;

        float x0f = floorf(gx), y0f = floorf(gy);
        float wx1 = gx - x0f, wy1 = gy - y0f;
        float wx0 = 1.f - wx1, wy0 = 1.f - wy1;

        int x0 = (int)x0f, y0 = (int)y0f;
        int cx = min(max(x0, 0), WM_ - 1);
        int cy = min(max(y0, 0), HM_ - 1);
        pixc[f] = (unsigned)(cy * WM_ + cx);

        wf[f][0] = wx0 * wy0;
        wf[f][1] = wx1 * wy0;
        wf[f][2] = wx0 * wy1;
        wf[f][3] = wx1 * wy1;

        bool e = (gx >= 2.f) && (gx <= (float)(WM_ - 2)) &&
                 (gy >= 2.f) && (gy <= (float)(HM_ - 2)) && inter;
        ff[f] = (e ? 1.f : 0.f) * validF[b * F_ + f];
    }

    size_t oidx = ((size_t)(b * D_ + d)) * HW_ + hw;

    // Wave-uniform early-out
    if (__ballot(ff[0] > 0.f || ff[1] > 0.f) == 0ull) {
        cvOut[oidx] = 0.f;
        return;
    }

    // broadcast f32 weight pairs
    f2 W00_0 = f2{wf[0][0], wf[0][0]}, W01_0 = f2{wf[0][1], wf[0][1]};
    f2 W10_0 = f2{wf[0][2], wf[0][2]}, W11_0 = f2{wf[0][3], wf[0][3]};
    f2 W00_1 = f2{wf[1][0], wf[1][0]}, W01_1 = f2{wf[1][1], wf[1][1]};
    f2 W10_1 = f2{wf[1][2], wf[1][2]}, W11_1 = f2{wf[1][3], wf[1][3]};

    const char* qbp = (const char*)quad4;
    const char* cbp = (const char*)cur4;
    unsigned oA = ((u32)((b * F_ + 0) * (C_ / 4)) * HW_ + pixc[0]) * 16u;
    unsigned oB = ((u32)((b * F_ + 1) * (C_ / 4)) * HW_ + pixc[1]) * 16u;
    unsigned oc = ((u32)(b * (C_ / 4)) * HW_ + (u32)hw) * 16u;

    f2 sA = f2{0.f, 0.f}, sB = f2{0.f, 0.f};

    #pragma unroll 4
    for (int c4i = 0; c4i < C_ / 4; ++c4i) {
        uint4 qa = *(const uint4*)(qbp + oA); oA += (u32)HW_ * 16u;
        uint4 qb = *(const uint4*)(qbp + oB); oB += (u32)HW_ * 16u;
        float4 cu = *(const float4*)(cbp + oc); oc += (u32)HW_ * 16u;

        f2 nc01; nc01.x = cu.x; nc01.y = cu.y;
        f2 nc23; nc23.x = cu.z; nc23.y = cu.w;

        f2 a01 = fp8pk<false>(qa.x) * W00_0 + (fp8pk<false>(qa.y) * W01_0 +
                 (fp8pk<false>(qa.z) * W10_0 + (fp8pk<false>(qa.w) * W11_0 + nc01)));
        f2 a23 = fp8pk<true >(qa.x) * W00_0 + (fp8pk<true >(qa.y) * W01_0 +
                 (fp8pk<true >(qa.z) * W10_0 + (fp8pk<true >(qa.w) * W11_0 + nc23)));
        f2 b01 = fp8pk<false>(qb.x) * W00_1 + (fp8pk<false>(qb.y) * W01_1 +
                 (fp8pk<false>(qb.z) * W10_1 + (fp8pk<false>(qb.w) * W11_1 + nc01)));
        f2 b23 = fp8pk<true >(qb.x) * W00_1 + (fp8pk<true >(qb.y) * W01_1 +
                 (fp8pk<true >(qb.z) * W10_1 + (fp8pk<true >(qb.w) * W11_1 + nc23)));

        sA.x += fabsf(a01.x); sA.y += fabsf(a01.y);
        sA.x += fabsf(a23.x); sA.y += fabsf(a23.y);
        sB.x += fabsf(b01.x); sB.y += fabsf(b01.y);
        sB.x += fabsf(b23.x); sB.y += fabsf(b23.y);
    }

    float s0 = sA.x + sA.y;
    float s1 = sB.x + sB.y;

    float m0 = s0 * (1.0f / 64.0f) * ff[0];
    float m1 = s1 * (1.0f / 64.0f) * ff[1];
    float costsum = m0 + m1;
    float counts  = ((m0 > 0.f) ? 1.f : 0.f) + ((m1 > 0.f) ? 1.f : 0.f);
    float scale = (counts > 1.5f) ? (1.0f / (2.0f + EPS_)) : (1.0f / (1.0f + EPS_));
    cvOut[oidx] = costsum * scale;
}

// ---------------------------------------------------------------------------
// Finalize: block = 64 pixels x 4 D-slices (one slice per wave). Each thread
// register-caches its 24 depths, LDS 4-way max combine, coalesced writes.
// ---------------------------------------------------------------------------
#define FDS_ 4
#define FDP_ (D_ / FDS_)   // 24

__global__ __launch_bounds__(256) void finalize(
    const float* __restrict__ cv,   // [B][D][HW]
    float* __restrict__ cost,       // [B][D][HW]
    float* __restrict__ missing)    // [B][D][HW]
{
    int slice = threadIdx.x >> 6;         // 0..3 (wave id)
    int lp    = threadIdx.x & 63;
    int p     = blockIdx.x * 64 + lp;     // 0..B*HW-1 (grid exact)
    int b = p / HW_, hw = p % HW_;
    const float* src = cv + (size_t)b * D_ * HW_ + (size_t)slice * FDP_ * HW_ + hw;

    float v[FDP_];
    float mx = 0.f;   // all values >= 0
    #pragma unroll
    for (int i = 0; i < FDP_; ++i) {
        v[i] = src[(size_t)i * HW_];
        mx = fmaxf(mx, v[i]);
    }

    __shared__ float lmax[FDS_][64];
    lmax[slice][lp] = mx;
    __syncthreads();
    mx = fmaxf(fmaxf(lmax[0][lp], lmax[1][lp]),
               fmaxf(lmax[2][lp], lmax[3][lp]));

    size_t obase = (size_t)b * D_ * HW_ + (size_t)slice * FDP_ * HW_ + hw;
    #pragma unroll
    for (int i = 0; i < FDP_; ++i) {
        float val = v[i];
        float m = (val == 0.f) ? 1.f : 0.f;
        size_t o = obase + (size_t)i * HW_;
        cost[o]    = (m != 0.f) ? mx : val;
        missing[o] = m;
    }
}

// ---------------------------------------------------------------------------
extern "C" void kernel_launch(void* const* d_in, const int* in_sizes, int n_in,
                              void* d_out, int out_size, void* d_ws, size_t ws_size,
                              hipStream_t stream)
{
    const float* current = (const float*)d_in[0];  // [B,C,H,W]
    const float* lookup  = (const float*)d_in[1];  // [B,F,C,H,W]
    const float* poses   = (const float*)d_in[2];  // [B,F,4,4]
    const float* K       = (const float*)d_in[3];  // [B,4,4]
    const float* invK    = (const float*)d_in[4];  // [B,4,4]

    float* out = (float*)d_out;
    float* costOut    = out;                 // [B,D,H,W]
    float* missingOut = out + NTOT;          // [B,D,H,W]
    float* cvOut      = out + 2 * NTOT;      // [B,D,H,W] (pre-fill cost)

    // workspace: params + 7.9 MB fp8 quad buffer
    float* ws     = (float*)d_ws;
    float* Pmat   = ws;                      // B*F*12 = 48 floats
    float* validF = Pmat + B_ * F_ * 12;     // B*F    = 4 floats
    uint4* quad4  = (uint4*)(ws + 64);       // B*F*(C/4)*HW * 16B = 7,864,320 B

    // cur4 stash lives in the costOut region (3.93 MB < 5.9 MB); it is
    // consumed by cost_volume and then overwritten by finalize.
    float4* cur4 = (float4*)costOut;

    const int npack = NQBLK4 + NCBLK;            // 480 + 960 = 1440
    hipLaunchKernelGGL(pack_and_setup, dim3(npack), dim3(256), 0, stream,
                       lookup, current, quad4, cur4, poses, K, Pmat, validF);

    const int nblocks = (HW_ / 64) * B_ * NDG_;  // 120 * 48 = 5760
    hipLaunchKernelGGL(cost_volume, dim3(nblocks), dim3(256), 0, stream,
                       quad4, cur4, invK, Pmat, validF, cvOut);

    const int nfin = (B_ * HW_) / 64;            // 240 blocks (256 thr: 64px x 4 slices)
    hipLaunchKernelGGL(finalize, dim3(nfin), dim3(256), 0, stream,
                       cvOut, costOut, missingOut);
}

// Round 15
// 58.454 us; speedup vs baseline: 1.0606x; 1.0108x over previous
//
#include <hip/hip_runtime.h>
#include <hip/hip_bf16.h>
#include <stdint.h>

#if __has_builtin(__builtin_amdgcn_cvt_pk_f32_fp8) && __has_builtin(__builtin_amdgcn_cvt_pk_fp8_f32)
#define HAS_HW_FP8 1
#else
#define HAS_HW_FP8 0
#include <hip/hip_fp8.h>
#endif

// Problem constants (from reference)
#define B_  2
#define F_  2
#define C_  64
#define D_  96
#define HM_ 48
#define WM_ 160
#define HW_ (HM_ * WM_)                 // 7680
#define NTOT ((size_t)B_ * D_ * HW_)    // 1,474,560 per output tensor
#define EPS_ 1e-7f
#define DW_  4                          // depths per block (one per wave)
#define NDG_ (D_ / DW_)                 // 24 depth groups

typedef float f2 __attribute__((ext_vector_type(2)));
typedef unsigned int u32;

// fp8 quad entry (16B): .x=p00, .y=p01, .z=p10, .w=p11; each u32 = 4 channels
// (c0..c3) as e4m3 bytes.

__device__ __forceinline__ u32 pk4_fp8(float a, float b, float c, float d) {
#if HAS_HW_FP8
    int r = __builtin_amdgcn_cvt_pk_fp8_f32(a, b, 0, false);
    r = __builtin_amdgcn_cvt_pk_fp8_f32(c, d, r, true);
    return (u32)r;
#else
    __hip_fp8_e4m3 qa(a), qb(b), qc(c), qd(d);
    return (u32)qa.__x | ((u32)qb.__x << 8) | ((u32)qc.__x << 16) |
           ((u32)qd.__x << 24);
#endif
}

template <bool HI>
__device__ __forceinline__ f2 fp8pk(u32 v) {
#if HAS_HW_FP8
    return __builtin_amdgcn_cvt_pk_f32_fp8((int)v, HI);
#else
    u32 w = HI ? (v >> 16) : v;
    __hip_fp8_e4m3 q0, q1;
    q0.__x = (uint8_t)(w & 0xff);
    q1.__x = (uint8_t)((w >> 8) & 0xff);
    f2 r; r.x = (float)q0; r.y = (float)q1;
    return r;
#endif
}

// Packed f32 FMA: d = a*b + c on a 64-bit register pair (1 instr for 2 lanes'
// worth of math). Bit-identical to the 2x v_fma_f32 the compiler would emit
// (same IEEE fma), just half the instruction count.
__device__ __forceinline__ f2 pkfma(f2 a, f2 b, f2 c) {
    f2 d;
    asm("v_pk_fma_f32 %0, %1, %2, %3" : "=v"(d) : "v"(a), "v"(b), "v"(c));
    return d;
}

#define NQBLK4 ((B_ * F_ * (C_/4) * (HW_/4)) / 256)  // 480
#define NCBLK  ((B_ * (C_/4) * HW_) / 256)           // 960

// ---------------------------------------------------------------------------
// Pack:
//  * quad4 [n][C/4][HW] (16B): corner-major fp8 quads, 4 channels per entry.
//    4 pixels per thread via aligned float4 row loads.
//  * cur4  [b][C/4][HW] (16B float4): 4 NEGATED f32 cur channels
// Block 0 also computes P = (K@T)[:3] and pose validity.
// ---------------------------------------------------------------------------
__global__ __launch_bounds__(256) void pack_and_setup(
    const float* __restrict__ look,   // [B*F*C][HW]
    const float* __restrict__ cur,    // [B*C][HW]
    uint4* __restrict__ quad4,
    float4* __restrict__ cur4,
    const float* __restrict__ poses,
    const float* __restrict__ K,
    float* __restrict__ Pout,         // [B*F][12]
    float* __restrict__ validOut)     // [B*F]
{
    if (blockIdx.x == 0 && threadIdx.x < 64) {
        int t = threadIdx.x;
        if (t < B_ * F_ * 12) {
            int j  = t & 3;
            int i  = (t >> 2) % 3;
            int bf = t / 12;
            int b  = bf / F_;
            const float* Kb = K + (size_t)b * 16;
            const float* T  = poses + (size_t)bf * 16;
            float s = 0.f;
            #pragma unroll
            for (int k = 0; k < 4; ++k) s += Kb[i * 4 + k] * T[k * 4 + j];
            Pout[bf * 12 + i * 4 + j] = s;
        }
        if (t < B_ * F_) {
            const float* T = poses + (size_t)t * 16;
            float s = 0.f;
            #pragma unroll
            for (int k = 0; k < 16; ++k) s += T[k];
            validOut[t] = (s != 0.0f) ? 1.0f : 0.0f;
        }
    }

    int blk = blockIdx.x;
    if (blk < NQBLK4) {
        int t   = blk * 256 + threadIdx.x;     // B*F*(C/4)*(HW/4)
        int g   = t % (HW_ / 4);               // 4-pixel group (same row)
        int rem = t / (HW_ / 4);
        int c4  = rem % (C_ / 4);
        int n   = rem / (C_ / 4);
        int x0 = (g * 4) % WM_;
        int y  = (g * 4) / WM_;
        int y1 = min(y + 1, HM_ - 1);
        int xe = min(x0 + 4, WM_ - 1);

        const float* base = look + ((size_t)n * C_ + 4 * c4) * HW_;
        float4 rA[4], rB[4];
        float  eA[4], eB[4];
        #pragma unroll
        for (int k = 0; k < 4; ++k) {
            const float* bc = base + (size_t)k * HW_;
            rA[k] = *(const float4*)(bc + y  * WM_ + x0);
            eA[k] = bc[y  * WM_ + xe];
            rB[k] = *(const float4*)(bc + y1 * WM_ + x0);
            eB[k] = bc[y1 * WM_ + xe];
        }
        const float* fA[4] = {(const float*)&rA[0], (const float*)&rA[1],
                              (const float*)&rA[2], (const float*)&rA[3]};
        const float* fB[4] = {(const float*)&rB[0], (const float*)&rB[1],
                              (const float*)&rB[2], (const float*)&rB[3]};

        uint4* outp = quad4 + ((size_t)(n * (C_ / 4) + c4)) * HW_ + g * 4;
        #pragma unroll
        for (int j = 0; j < 4; ++j) {
            float p01_0 = (j < 3) ? fA[0][j + 1] : eA[0];
            float p01_1 = (j < 3) ? fA[1][j + 1] : eA[1];
            float p01_2 = (j < 3) ? fA[2][j + 1] : eA[2];
            float p01_3 = (j < 3) ? fA[3][j + 1] : eA[3];
            float p11_0 = (j < 3) ? fB[0][j + 1] : eB[0];
            float p11_1 = (j < 3) ? fB[1][j + 1] : eB[1];
            float p11_2 = (j < 3) ? fB[2][j + 1] : eB[2];
            float p11_3 = (j < 3) ? fB[3][j + 1] : eB[3];
            uint4 q;
            q.x = pk4_fp8(fA[0][j], fA[1][j], fA[2][j], fA[3][j]);
            q.y = pk4_fp8(p01_0,    p01_1,    p01_2,    p01_3);
            q.z = pk4_fp8(fB[0][j], fB[1][j], fB[2][j], fB[3][j]);
            q.w = pk4_fp8(p11_0,    p11_1,    p11_2,    p11_3);
            outp[j] = q;
        }
    } else {
        int t   = (blk - NQBLK4) * 256 + threadIdx.x;  // B*(C/4)*HW
        int pix = t % HW_;
        int rem = t / HW_;
        int c4  = rem % (C_ / 4);
        int b   = rem / (C_ / 4);
        const float* p = cur + ((size_t)b * C_ + 4 * c4) * HW_ + pix;
        float4 h;
        h.x = -p[0];
        h.y = -p[(size_t)HW_];
        h.z = -p[2 * (size_t)HW_];
        h.w = -p[3 * (size_t)HW_];
        cur4[t] = h;
    }
}

// ---------------------------------------------------------------------------
// Main cost-volume kernel (r14 structure; f2 FMA chains forced to
// v_pk_fma_f32 via inline asm -- 16 packed FMA/iter instead of 32 scalar).
// ---------------------------------------------------------------------------
__global__ __launch_bounds__(256) void cost_volume(
    const uint4* __restrict__ quad4,   // [B*F][C/4][HW]
    const float4* __restrict__ cur4,   // [B][C/4][HW] negated f32
    const float* __restrict__ invK,    // [B][16]
    const float* __restrict__ P,       // [B*F][12]
    const float* __restrict__ validF,  // [B*F]
    float* __restrict__ cvOut)         // [B][D][HW]
{
    int blk  = blockIdx.x;             // 5760 = 120 tile64 * (B_*NDG_)
    int tile = blk / (B_ * NDG_);
    int r    = blk % (B_ * NDG_);
    int b    = r / NDG_;
    int dg   = r % NDG_;
    int wave = threadIdx.x >> 6;
    int lane = threadIdx.x & 63;
    int d    = dg * DW_ + wave;
    int hw   = tile * 64 + lane;

    int x = hw % WM_, y = hw / WM_;
    float fx = (float)x, fy = (float)y;

    const float* ik = invK + (size_t)b * 16;
    float rx = ik[0] * fx + ik[1] * fy + ik[2];
    float ry = ik[4] * fx + ik[5] * fy + ik[6];
    float rz = ik[8] * fx + ik[9] * fy + ik[10];

    float depth = 0.1f + (float)d * (19.9f / 95.0f);
    float qx = depth * rx, qy = depth * ry, qz = depth * rz;

    bool inter = (x >= 2 && x <= WM_ - 3 && y >= 2 && y <= HM_ - 3);

    unsigned pixc[F_];
    float wf[F_][4];
    float ff[F_];

    #pragma unroll
    for (int f = 0; f < F_; ++f) {
        const float* Pf = P + (size_t)(b * F_ + f) * 12;
        float cp0 = Pf[0] * qx + Pf[1] * qy + Pf[2]  * qz + Pf[3];
        float cp1 = Pf[4] * qx + Pf[5] * qy + Pf[6]  * qz + Pf[7];
        float cp2 = Pf[8] * qx + Pf[9] * qy + Pf[10] * qz + Pf[11];
        float z  = cp2 + EPS_;
        float gx = cp0 / z, gy = cp1 / z;

        float x0f = floorf(gx), y0f = floorf(gy);
        float wx1 = gx - x0f, wy1 = gy - y0f;
        float wx0 = 1.f - wx1, wy0 = 1.f - wy1;

        int x0 = (int)x0f, y0 = (int)y0f;
        int cx = min(max(x0, 0), WM_ - 1);
        int cy = min(max(y0, 0), HM_ - 1);
        pixc[f] = (unsigned)(cy * WM_ + cx);

        wf[f][0] = wx0 * wy0;
        wf[f][1] = wx1 * wy0;
        wf[f][2] = wx0 * wy1;
        wf[f][3] = wx1 * wy1;

        bool e = (gx >= 2.f) && (gx <= (float)(WM_ - 2)) &&
                 (gy >= 2.f) && (gy <= (float)(HM_ - 2)) && inter;
        ff[f] = (e ? 1.f : 0.f) * validF[b * F_ + f];
    }

    size_t oidx = ((size_t)(b * D_ + d)) * HW_ + hw;

    // Wave-uniform early-out
    if (__ballot(ff[0] > 0.f || ff[1] > 0.f) == 0ull) {
        cvOut[oidx] = 0.f;
        return;
    }

    // broadcast f32 weight pairs
    f2 W00_0 = f2{wf[0][0], wf[0][0]}, W01_0 = f2{wf[0][1], wf[0][1]};
    f2 W10_0 = f2{wf[0][2], wf[0][2]}, W11_0 = f2{wf[0][3], wf[0][3]};
    f2 W00_1 = f2{wf[1][0], wf[1][0]}, W01_1 = f2{wf[1][1], wf[1][1]};
    f2 W10_1 = f2{wf[1][2], wf[1][2]}, W11_1 = f2{wf[1][3], wf[1][3]};

    const char* qbp = (const char*)quad4;
    const char* cbp = (const char*)cur4;
    unsigned oA = ((u32)((b * F_ + 0) * (C_ / 4)) * HW_ + pixc[0]) * 16u;
    unsigned oB = ((u32)((b * F_ + 1) * (C_ / 4)) * HW_ + pixc[1]) * 16u;
    unsigned oc = ((u32)(b * (C_ / 4)) * HW_ + (u32)hw) * 16u;

    f2 sA = f2{0.f, 0.f}, sB = f2{0.f, 0.f};

    #pragma unroll 4
    for (int c4i = 0; c4i < C_ / 4; ++c4i) {
        uint4 qa = *(const uint4*)(qbp + oA); oA += (u32)HW_ * 16u;
        uint4 qb = *(const uint4*)(qbp + oB); oB += (u32)HW_ * 16u;
        float4 cu = *(const float4*)(cbp + oc); oc += (u32)HW_ * 16u;

        f2 nc01; nc01.x = cu.x; nc01.y = cu.y;
        f2 nc23; nc23.x = cu.z; nc23.y = cu.w;

        f2 a01 = pkfma(fp8pk<false>(qa.x), W00_0,
                 pkfma(fp8pk<false>(qa.y), W01_0,
                 pkfma(fp8pk<false>(qa.z), W10_0,
                 pkfma(fp8pk<false>(qa.w), W11_0, nc01))));
        f2 a23 = pkfma(fp8pk<true >(qa.x), W00_0,
                 pkfma(fp8pk<true >(qa.y), W01_0,
                 pkfma(fp8pk<true >(qa.z), W10_0,
                 pkfma(fp8pk<true >(qa.w), W11_0, nc23))));
        f2 b01 = pkfma(fp8pk<false>(qb.x), W00_1,
                 pkfma(fp8pk<false>(qb.y), W01_1,
                 pkfma(fp8pk<false>(qb.z), W10_1,
                 pkfma(fp8pk<false>(qb.w), W11_1, nc01))));
        f2 b23 = pkfma(fp8pk<true >(qb.x), W00_1,
                 pkfma(fp8pk<true >(qb.y), W01_1,
                 pkfma(fp8pk<true >(qb.z), W10_1,
                 pkfma(fp8pk<true >(qb.w), W11_1, nc23))));

        sA.x += fabsf(a01.x); sA.y += fabsf(a01.y);
        sA.x += fabsf(a23.x); sA.y += fabsf(a23.y);
        sB.x += fabsf(b01.x); sB.y += fabsf(b01.y);
        sB.x += fabsf(b23.x); sB.y += fabsf(b23.y);
    }

    float s0 = sA.x + sA.y;
    float s1 = sB.x + sB.y;

    float m0 = s0 * (1.0f / 64.0f) * ff[0];
    float m1 = s1 * (1.0f / 64.0f) * ff[1];
    float costsum = m0 + m1;
    float counts  = ((m0 > 0.f) ? 1.f : 0.f) + ((m1 > 0.f) ? 1.f : 0.f);
    float scale = (counts > 1.5f) ? (1.0f / (2.0f + EPS_)) : (1.0f / (1.0f + EPS_));
    cvOut[oidx] = costsum * scale;
}

// ---------------------------------------------------------------------------
// Finalize: block = 64 pixels x 4 D-slices (one slice per wave). Each thread
// register-caches its 24 depths, LDS 4-way max combine, coalesced writes.
// ---------------------------------------------------------------------------
#define FDS_ 4
#define FDP_ (D_ / FDS_)   // 24

__global__ __launch_bounds__(256) void finalize(
    const float* __restrict__ cv,   // [B][D][HW]
    float* __restrict__ cost,       // [B][D][HW]
    float* __restrict__ missing)    // [B][D][HW]
{
    int slice = threadIdx.x >> 6;         // 0..3 (wave id)
    int lp    = threadIdx.x & 63;
    int p     = blockIdx.x * 64 + lp;     // 0..B*HW-1 (grid exact)
    int b = p / HW_, hw = p % HW_;
    const float* src = cv + (size_t)b * D_ * HW_ + (size_t)slice * FDP_ * HW_ + hw;

    float v[FDP_];
    float mx = 0.f;   // all values >= 0
    #pragma unroll
    for (int i = 0; i < FDP_; ++i) {
        v[i] = src[(size_t)i * HW_];
        mx = fmaxf(mx, v[i]);
    }

    __shared__ float lmax[FDS_][64];
    lmax[slice][lp] = mx;
    __syncthreads();
    mx = fmaxf(fmaxf(lmax[0][lp], lmax[1][lp]),
               fmaxf(lmax[2][lp], lmax[3][lp]));

    size_t obase = (size_t)b * D_ * HW_ + (size_t)slice * FDP_ * HW_ + hw;
    #pragma unroll
    for (int i = 0; i < FDP_; ++i) {
        float val = v[i];
        float m = (val == 0.f) ? 1.f : 0.f;
        size_t o = obase + (size_t)i * HW_;
        cost[o]    = (m != 0.f) ? mx : val;
        missing[o] = m;
    }
}

// ---------------------------------------------------------------------------
extern "C" void kernel_launch(void* const* d_in, const int* in_sizes, int n_in,
                              void* d_out, int out_size, void* d_ws, size_t ws_size,
                              hipStream_t stream)
{
    const float* current = (const float*)d_in[0];  // [B,C,H,W]
    const float* lookup  = (const float*)d_in[1];  // [B,F,C,H,W]
    const float* poses   = (const float*)d_in[2];  // [B,F,4,4]
    const float* K       = (const float*)d_in[3];  // [B,4,4]
    const float* invK    = (const float*)d_in[4];  // [B,4,4]

    float* out = (float*)d_out;
    float* costOut    = out;                 // [B,D,H,W]
    float* missingOut = out + NTOT;          // [B,D,H,W]
    float* cvOut      = out + 2 * NTOT;      // [B,D,H,W] (pre-fill cost)

    // workspace: params + 7.9 MB fp8 quad buffer
    float* ws     = (float*)d_ws;
    float* Pmat   = ws;                      // B*F*12 = 48 floats
    float* validF = Pmat + B_ * F_ * 12;     // B*F    = 4 floats
    uint4* quad4  = (uint4*)(ws + 64);       // B*F*(C/4)*HW * 16B = 7,864,320 B

    // cur4 stash lives in the costOut region (3.93 MB < 5.9 MB); it is
    // consumed by cost_volume and then overwritten by finalize.
    float4* cur4 = (float4*)costOut;

    const int npack = NQBLK4 + NCBLK;            // 480 + 960 = 1440
    hipLaunchKernelGGL(pack_and_setup, dim3(npack), dim3(256), 0, stream,
                       lookup, current, quad4, cur4, poses, K, Pmat, validF);

    const int nblocks = (HW_ / 64) * B_ * NDG_;  // 120 * 48 = 5760
    hipLaunchKernelGGL(cost_volume, dim3(nblocks), dim3(256), 0, stream,
                       quad4, cur4, invK, Pmat, validF, cvOut);

    const int nfin = (B_ * HW_) / 64;            // 240 blocks (256 thr: 64px x 4 slices)
    hipLaunchKernelGGL(finalize, dim3(nfin), dim3(256), 0, stream,
                       cvOut, costOut, missingOut);
}